// Round 1
// 633.764 us; speedup vs baseline: 1.1416x; 1.1416x over previous
//
#include <hip/hip_runtime.h>
#include <stdint.h>

#define B_TOTAL 4096
#define T_STEPS 512
#define IN_DIM 16
#define H1 5
#define H2 50
#define NCLS 20

typedef __attribute__((ext_vector_type(8))) short bf16x8;
typedef __attribute__((ext_vector_type(4))) float f32x4;

#define LOG2E 1.44269504f
#define C2L   2.88539008f   /* 2*log2(e) */

// sigma(y_scaled)   = rcp1pexp2(-y)          (weights pre-scaled by LOG2E)
// tanh(y_scaled)    = fma(-2, rcp1pexp2(y),1) (weights pre-scaled by 2*LOG2E)
__device__ inline float rcp1pexp2(float y){
  return __builtin_amdgcn_rcpf(1.0f + __builtin_amdgcn_exp2f(y));
}

// dword = [top16(a) | top16(b)]  (memory shorts: [0]=b, [1]=a)
__device__ inline unsigned pack_top(float a, float b){
  return __builtin_amdgcn_perm(__float_as_uint(a), __float_as_uint(b), 0x07060302u);
}
__device__ inline void cvt_store(unsigned short* dh, unsigned short* dl, float4 v){
  uint2 H, L;
  H.x = pack_top(v.y, v.x);
  H.y = pack_top(v.w, v.z);
  float r0 = v.x - __uint_as_float(__float_as_uint(v.x) & 0xFFFF0000u);
  float r1 = v.y - __uint_as_float(__float_as_uint(v.y) & 0xFFFF0000u);
  float r2 = v.z - __uint_as_float(__float_as_uint(v.z) & 0xFFFF0000u);
  float r3 = v.w - __uint_as_float(__float_as_uint(v.w) & 0xFFFF0000u);
  L.x = pack_top(r1, r0);
  L.y = pack_top(r3, r2);
  *(uint2*)dh = H; *(uint2*)dl = L;
}
__device__ inline void split1(float h, unsigned short& hi, unsigned short& lo){
  unsigned u = __float_as_uint(h);
  hi = (unsigned short)(u >> 16);
  float r = h - __uint_as_float(u & 0xFFFF0000u);
  lo = (unsigned short)(__float_as_uint(r) >> 16);
}
__device__ inline void wsplit(float w, short& hi, short& lo){
  unsigned u = __float_as_uint(w);
  hi = (short)(u >> 16);
  float r = w - __uint_as_float(u & 0xFFFF0000u);
  lo = (short)(__float_as_uint(r) >> 16);
}

// raw barrier: no vmcnt drain (x prefetch stays in flight), LDS made visible
// by explicit lgkmcnt(0) before the barrier.
#define LDS_FENCE() __asm__ volatile("s_waitcnt lgkmcnt(0)" ::: "memory")
#define BARRIER()   __asm__ volatile("s_barrier" ::: "memory")

// Fused 2-layer LSTM + FC. grid 256 (16-batch tiles), block 320 (5 waves).
// ONE raw s_barrier per superstep. Waves 0-3: lstm2 (16 cell-cols each).
// Wave 4: lstm1, one step AHEAD. a2 double-buffered: superstep t reads a2[t&1],
// writes a2[(t+1)&1]. t-loop unrolled x2 so the buffer parity is compile-time.
// Activation scales are folded into weights/biases (i,f,o: *LOG2E; g: *2LOG2E);
// the c-state is kept pre-scaled by 2LOG2E so tanh(c) needs no multiply.
// Per gate: two depth-3 MFMA chains seeded with bias / zero as C-in.
__global__ __launch_bounds__(320, 1) void lstm_fused_kernel(
    const float* __restrict__ x,
    const float* __restrict__ w_ih1, const float* __restrict__ w_hh1,
    const float* __restrict__ b_ih1, const float* __restrict__ b_hh1,
    const float* __restrict__ w_ih2, const float* __restrict__ w_hh2,
    const float* __restrict__ b_ih2, const float* __restrict__ b_hh2,
    const float* __restrict__ fc_w, const float* __restrict__ fc_b,
    float* __restrict__ out)
{
  const int tid  = threadIdx.x;
  const int lane = tid & 63;
  const int wave = tid >> 6;      // 0..3 lstm2, 4 lstm1
  const int l15  = lane & 15;
  const int quad = lane >> 4;
  const int b0   = blockIdx.x * 16;

  // a2[buf][batch16][col72]: h2 0-49 | h1 50-54 | zero 55-71
  __shared__ __align__(16) unsigned short a2h[2][16*72], a2l[2][16*72];
  // x ring: [slot8][batch16][col24] (dims 0-15; cols 16-23 never read)
  __shared__ __align__(16) unsigned short xrh[8][16*24], xrl[8][16*24];
  // lstm1 h state: [batch16][col24]: h1 0-4 | zero 5-15 (cols 16-23 unread)
  __shared__ __align__(16) unsigned short a1h[16*24], a1l[16*24];
  __shared__ float h2f[16*52];

  // ---- weights (registers, loop-invariant), split hi/lo bf16, pre-scaled ----
  bf16x8 Bh[4][2], Bl[4][2];
  float bias[4];
  float cst[4] = {0.f,0.f,0.f,0.f};   // c-state, pre-scaled by 2LOG2E
  const int cg = wave*16 + l15;       // lstm2 cell col (waves 0-3)

  if (wave < 4){
    bool valid = cg < H2;
#pragma unroll
    for (int tt=0; tt<4; ++tt){
      const float gsc = (tt == 2) ? C2L : LOG2E;
      int grow = tt*H2 + cg;
#pragma unroll
      for (int kt=0; kt<2; ++kt){
#pragma unroll
        for (int j=0;j<8;j++){
          int kk = kt*32 + quad*8 + j;
          float w = 0.f;
          if (valid){
            if (kk < H2)         w = w_hh2[grow*H2 + kk];
            else if (kk < H2+H1) w = w_ih2[grow*H1 + (kk-H2)];
          }
          w *= gsc;
          short hi, lo; wsplit(w, hi, lo);
          Bh[tt][kt][j] = hi; Bl[tt][kt][j] = lo;
        }
      }
      bias[tt] = valid ? gsc * (b_ih2[grow] + b_hh2[grow]) : 0.f;
    }
  } else {
    bool valid = l15 < H1;
#pragma unroll
    for (int tt=0; tt<4; ++tt){
      const float gsc = (tt == 2) ? C2L : LOG2E;
      int grow = tt*H1 + l15;
#pragma unroll
      for (int j=0;j<8;j++){
        int kk = quad*8 + j;
        float w = 0.f;
        if (valid){
          if (kk < IN_DIM)         w = w_ih1[grow*IN_DIM + kk];
          else if (kk < IN_DIM+H1) w = w_hh1[grow*H1 + (kk-IN_DIM)];
        }
        w *= gsc;
        short hi, lo; wsplit(w, hi, lo);
        Bh[tt][0][j] = hi; Bl[tt][0][j] = lo;
        Bh[tt][1][j] = 0;  Bl[tt][1][j] = 0;
      }
      bias[tt] = valid ? gsc * (b_ih1[grow] + b_hh1[grow]) : 0.f;
    }
  }

  // invariant C-in vectors for MFMA chain seeding
  f32x4 biasv[4];
#pragma unroll
  for (int tt=0; tt<4; ++tt){
    biasv[tt][0] = bias[tt]; biasv[tt][1] = bias[tt];
    biasv[tt][2] = bias[tt]; biasv[tt][3] = bias[tt];
  }
  const f32x4 zero4 = {0.f,0.f,0.f,0.f};

  // ---- zero LDS state ----
  { unsigned short* p = &a2h[0][0]; for (int i=tid;i<2*16*72;i+=320) p[i]=0; }
  { unsigned short* p = &a2l[0][0]; for (int i=tid;i<2*16*72;i+=320) p[i]=0; }
  { unsigned short* p = &a1h[0];    for (int i=tid;i<16*24;i+=320)   p[i]=0; }
  { unsigned short* p = &a1l[0];    for (int i=tid;i<16*24;i+=320)   p[i]=0; }

  // preload x(0..7) into ring (wave 4, private)
  const int xb = lane >> 2;        // batch
  const int xd = (lane & 3) * 4;   // dim base
  if (wave == 4){
#pragma unroll
    for (int s=0;s<8;s++){
      float4 v = *(const float4*)&x[((size_t)(b0+xb)*T_STEPS + s)*IN_DIM + xd];
      cvt_store(&xrh[s][xb*24+xd], &xrl[s][xb*24+xd], v);
    }
  }
  __syncthreads();   // one-time: zeros + ring visible

  float4 pf0, pf1, pf2, pf3;
  bool pend = false;

#define ACT_BLOCK(ACC_, HV_) \
    _Pragma("unroll") \
    for (int r=0;r<4;r++){ \
      float gi = rcp1pexp2(-ACC_[0][r]); \
      float gf = rcp1pexp2(-ACC_[1][r]); \
      float gg = fmaf(-2.0f, rcp1pexp2(ACC_[2][r]), 1.0f); \
      float go = rcp1pexp2(-ACC_[3][r]); \
      cst[r] = fmaf(gf, cst[r], gi * (C2L * gg)); \
      HV_[r] = go * fmaf(-2.0f, rcp1pexp2(cst[r]), 1.0f); \
    }

#define LSTM2_BODY(T_, RD_, WR_) do { \
    const int rb = l15*72; \
    bf16x8 ah0 = *(const bf16x8*)&a2h[RD_][rb +      quad*8]; \
    bf16x8 al0 = *(const bf16x8*)&a2l[RD_][rb +      quad*8]; \
    bf16x8 ah1 = *(const bf16x8*)&a2h[RD_][rb + 32 + quad*8]; \
    bf16x8 al1 = *(const bf16x8*)&a2l[RD_][rb + 32 + quad*8]; \
    f32x4 acc[4]; \
    _Pragma("unroll") \
    for (int tt=0; tt<4; ++tt){ \
      f32x4 c0 = __builtin_amdgcn_mfma_f32_16x16x32_bf16(ah0, Bh[tt][0], biasv[tt], 0,0,0); \
      c0 = __builtin_amdgcn_mfma_f32_16x16x32_bf16(al0, Bh[tt][0], c0, 0,0,0); \
      c0 = __builtin_amdgcn_mfma_f32_16x16x32_bf16(ah0, Bl[tt][0], c0, 0,0,0); \
      f32x4 c1 = __builtin_amdgcn_mfma_f32_16x16x32_bf16(ah1, Bh[tt][1], zero4, 0,0,0); \
      c1 = __builtin_amdgcn_mfma_f32_16x16x32_bf16(al1, Bh[tt][1], c1, 0,0,0); \
      c1 = __builtin_amdgcn_mfma_f32_16x16x32_bf16(ah1, Bl[tt][1], c1, 0,0,0); \
      acc[tt] = c0 + c1; \
    } \
    float hv[4]; \
    ACT_BLOCK(acc, hv) \
    if (cg < H2){ \
      const int wrb = quad*4*72 + cg; \
      _Pragma("unroll") \
      for (int r=0;r<4;r++){ \
        unsigned short hh, hl; split1(hv[r], hh, hl); \
        a2h[WR_][wrb + r*72] = hh; \
        a2l[WR_][wrb + r*72] = hl; \
      } \
      if ((T_) == T_STEPS-1){ \
        _Pragma("unroll") \
        for (int r=0;r<4;r++){ \
          out[(size_t)B_TOTAL*NCLS + (size_t)(b0+quad*4+r)*H2 + cg] = hv[r]; \
          h2f[(quad*4+r)*52 + cg] = hv[r]; \
        } \
      } \
    } \
  } while(0)

#define LSTM1_BODY(T_, WR_) do { \
    const int s = (T_) + 1; \
    if (s < T_STEPS){ \
      if ((s & 3) == 0 && s+4 < T_STEPS){ \
        const float* xp = &x[((size_t)(b0+xb)*T_STEPS + (s+4))*IN_DIM + xd]; \
        pf0 = *(const float4*)(xp + 0*IN_DIM); \
        pf1 = *(const float4*)(xp + 1*IN_DIM); \
        pf2 = *(const float4*)(xp + 2*IN_DIM); \
        pf3 = *(const float4*)(xp + 3*IN_DIM); \
        pend = true; \
      } \
      const int slot = s & 7; \
      bf16x8 ah, al; \
      if (quad < 2){ \
        ah = *(const bf16x8*)&xrh[slot][l15*24 + quad*8]; \
        al = *(const bf16x8*)&xrl[slot][l15*24 + quad*8]; \
      } else { \
        ah = *(const bf16x8*)&a1h[l15*24 + (quad-2)*8]; \
        al = *(const bf16x8*)&a1l[l15*24 + (quad-2)*8]; \
      } \
      f32x4 acc[4]; \
      _Pragma("unroll") \
      for (int tt=0; tt<4; ++tt){ \
        f32x4 c0 = __builtin_amdgcn_mfma_f32_16x16x32_bf16(ah, Bh[tt][0], biasv[tt], 0,0,0); \
        c0 = __builtin_amdgcn_mfma_f32_16x16x32_bf16(al, Bh[tt][0], c0, 0,0,0); \
        c0 = __builtin_amdgcn_mfma_f32_16x16x32_bf16(ah, Bl[tt][0], c0, 0,0,0); \
        acc[tt] = c0; \
      } \
      float hv[4]; \
      ACT_BLOCK(acc, hv) \
      if (l15 < H1){ \
        _Pragma("unroll") \
        for (int r=0;r<4;r++){ \
          unsigned short hh, hl; split1(hv[r], hh, hl); \
          const int row = quad*4 + r; \
          a1h[row*24 + l15] = hh; \
          a1l[row*24 + l15] = hl; \
          a2h[WR_][row*72 + H2 + l15] = hh; \
          a2l[WR_][row*72 + H2 + l15] = hl; \
        } \
      } \
      if ((s & 3) == 2 && pend){ \
        cvt_store(&xrh[(s+2)&7][xb*24+xd], &xrl[(s+2)&7][xb*24+xd], pf0); \
        cvt_store(&xrh[(s+3)&7][xb*24+xd], &xrl[(s+3)&7][xb*24+xd], pf1); \
        cvt_store(&xrh[(s+4)&7][xb*24+xd], &xrl[(s+4)&7][xb*24+xd], pf2); \
        cvt_store(&xrh[(s+5)&7][xb*24+xd], &xrl[(s+5)&7][xb*24+xd], pf3); \
        pend = false; \
      } \
    } \
  } while(0)

  // peel t=-1: wave4 computes h1(0) into a2[0]
  if (wave == 4) LSTM1_BODY(-1, 0);
  LDS_FENCE(); BARRIER();

  // main loop, unrolled x2: compile-time buffer parity (rd,wr) = (0,1),(1,0)
  for (int t2 = 0; t2 < T_STEPS; t2 += 2){
    if (wave == 4) LSTM1_BODY(t2, 1);
    else           LSTM2_BODY(t2, 0, 1);
    LDS_FENCE(); BARRIER();
    if (wave == 4) LSTM1_BODY(t2+1, 0);
    else           LSTM2_BODY(t2+1, 1, 0);
    LDS_FENCE(); BARRIER();
  }

#undef LSTM2_BODY
#undef LSTM1_BODY
#undef ACT_BLOCK

  __syncthreads();
  // fused FC: 16 batches x 20 outputs = 320 threads exactly
  {
    int b = tid / 20, o = tid % 20;
    float s = fc_b[o];
#pragma unroll 10
    for (int k=0;k<H2;k++) s += fc_w[o*H2+k] * h2f[b*52+k];
    out[(size_t)(b0+b)*NCLS + o] = s;
  }
}

extern "C" void kernel_launch(void* const* d_in, const int* in_sizes, int n_in,
                              void* d_out, int out_size, void* d_ws, size_t ws_size,
                              hipStream_t stream) {
  const float* x     = (const float*)d_in[0];
  const float* w_ih1 = (const float*)d_in[1];
  const float* w_hh1 = (const float*)d_in[2];
  const float* b_ih1 = (const float*)d_in[3];
  const float* b_hh1 = (const float*)d_in[4];
  const float* w_ih2 = (const float*)d_in[5];
  const float* w_hh2 = (const float*)d_in[6];
  const float* b_ih2 = (const float*)d_in[7];
  const float* b_hh2 = (const float*)d_in[8];
  const float* fc_w  = (const float*)d_in[9];
  const float* fc_b  = (const float*)d_in[10];
  float* out = (float*)d_out;

  lstm_fused_kernel<<<dim3(B_TOTAL/16), dim3(320), 0, stream>>>(
      x, w_ih1, w_hh1, b_ih1, b_hh1, w_ih2, w_hh2, b_ih2, b_hh2, fc_w, fc_b, out);
}

// Round 2
// 605.077 us; speedup vs baseline: 1.1957x; 1.0474x over previous
//
#include <hip/hip_runtime.h>
#include <stdint.h>

#define B_TOTAL 4096
#define T_STEPS 512
#define IN_DIM 16
#define H1 5
#define H2 50
#define NCLS 20

typedef __attribute__((ext_vector_type(8))) short bf16x8;
typedef __attribute__((ext_vector_type(4))) float f32x4;

#define LOG2E 1.44269504f
#define C2L   2.88539008f   /* 2*log2(e) */
#define C2L2  5.77078016f   /* 4*log2(e) */

// sigma(y_scaled) = rcp1pexp2(-y)            (weights pre-scaled by LOG2E)
// tanh(y_scaled)  = fma(-2, rcp1pexp2(y), 1) (weights pre-scaled by 2*LOG2E)
__device__ inline float rcp1pexp2(float y){
  return __builtin_amdgcn_rcpf(1.0f + __builtin_amdgcn_exp2f(y));
}

__device__ inline void split1(float h, unsigned short& hi, unsigned short& lo){
  unsigned u = __float_as_uint(h);
  hi = (unsigned short)(u >> 16);
  float r = h - __uint_as_float(u & 0xFFFF0000u);
  lo = (unsigned short)(__float_as_uint(r) >> 16);
}
__device__ inline void wsplit(float w, short& hi, short& lo){
  unsigned u = __float_as_uint(w);
  hi = (short)(u >> 16);
  float r = w - __uint_as_float(u & 0xFFFF0000u);
  lo = (short)(__float_as_uint(r) >> 16);
}
// split 8 floats (two float4 = dims q*8..q*8+7) into hi/lo bf16x8 fragments
__device__ inline void xsplit(float4 a, float4 b, bf16x8& H, bf16x8& L){
  short h,l;
  wsplit(a.x,h,l); H[0]=h; L[0]=l;
  wsplit(a.y,h,l); H[1]=h; L[1]=l;
  wsplit(a.z,h,l); H[2]=h; L[2]=l;
  wsplit(a.w,h,l); H[3]=h; L[3]=l;
  wsplit(b.x,h,l); H[4]=h; L[4]=l;
  wsplit(b.y,h,l); H[5]=h; L[5]=l;
  wsplit(b.z,h,l); H[6]=h; L[6]=l;
  wsplit(b.w,h,l); H[7]=h; L[7]=l;
}

// raw barrier: no vmcnt drain (x prefetch stays in flight); LDS made visible
// by explicit lgkmcnt(0) before the barrier.
#define LDS_FENCE() __asm__ volatile("s_waitcnt lgkmcnt(0)" ::: "memory")
#define BARRIER()   __asm__ volatile("s_barrier" ::: "memory")

// Fused 2-layer LSTM + FC. grid 256 (16-batch tiles), block 256 (4 waves,
// 1 wave/SIMD — no doubled SIMD). lstm1 is folded into wave 3's MFMA tiles:
// k-space = chunk0 h2[0..31] | chunk1 h2[32..49]+h1[50..54] | chunk2 x[0..15].
// Wave 3's 16 output cols = lstm2 cells 48,49 (l15 0,1) + lstm1 cells 0..4
// (l15 2..6); LDS write col = 48+l15 covers both. chunk2 (x) lives in
// registers only (XA/XB ping-pong across the x2-unrolled t loop; converted
// during the LDS-read latency window). At superstep t:
//   A(t) = [h2(t-1) | h1(t) | x(t+1)]; lstm2 cols -> h2(t); lstm1 -> h1(t+1).
// Peel computes h1(0) from x(0). One raw s_barrier per superstep.
// Activation scales folded into weights/biases (i,f,o: *LOG2E; g: *2LOG2E);
// c-state kept pre-scaled by 2LOG2E.
__global__ __launch_bounds__(256, 1) void lstm_fused_kernel(
    const float* __restrict__ x,
    const float* __restrict__ w_ih1, const float* __restrict__ w_hh1,
    const float* __restrict__ b_ih1, const float* __restrict__ b_hh1,
    const float* __restrict__ w_ih2, const float* __restrict__ w_hh2,
    const float* __restrict__ b_ih2, const float* __restrict__ b_hh2,
    const float* __restrict__ fc_w, const float* __restrict__ fc_b,
    float* __restrict__ out)
{
  const int tid  = threadIdx.x;
  const int lane = tid & 63;
  const int wave = tid >> 6;      // 0..3
  const int l15  = lane & 15;
  const int quad = lane >> 4;
  const int b0   = blockIdx.x * 16;

  // a2[buf][batch16][col72]: h2 0-49 | h1 50-54 | zero 55-63 | pad 64-71
  __shared__ __align__(16) unsigned short a2h[2][16*72], a2l[2][16*72];
  __shared__ float h2f[16*52];

  const bf16x8 zero8 = {0,0,0,0,0,0,0,0};
  const f32x4  zero4 = {0.f,0.f,0.f,0.f};

  bf16x8 Bh[4][3], Bl[4][3];
  f32x4 biasv[4];
  float cst[4] = {0.f,0.f,0.f,0.f};   // c-state, pre-scaled by 2LOG2E

#pragma unroll
  for (int tt=0; tt<4; ++tt)
#pragma unroll
    for (int kt=0; kt<3; ++kt){ Bh[tt][kt]=zero8; Bl[tt][kt]=zero8; }

  if (wave < 3){
    const int c = wave*16 + l15;    // lstm2 cell 0..47, always valid
#pragma unroll
    for (int tt=0; tt<4; ++tt){
      const float gsc = (tt == 2) ? C2L : LOG2E;
      const int grow = tt*H2 + c;
#pragma unroll
      for (int kt=0; kt<2; ++kt){
#pragma unroll
        for (int j=0;j<8;j++){
          const int kk = kt*32 + quad*8 + j;
          float w = 0.f;
          if (kk < H2)         w = w_hh2[grow*H2 + kk];
          else if (kk < H2+H1) w = w_ih2[grow*H1 + (kk-H2)];
          w *= gsc;
          short hi, lo; wsplit(w, hi, lo);
          Bh[tt][kt][j] = hi; Bl[tt][kt][j] = lo;
        }
      }
      const float bias = gsc * (b_ih2[grow] + b_hh2[grow]);
      biasv[tt][0]=bias; biasv[tt][1]=bias; biasv[tt][2]=bias; biasv[tt][3]=bias;
    }
  } else {
    // wave 3: cols l15 0,1 -> lstm2 cells 48,49; l15 2..6 -> lstm1 cells 0..4
#pragma unroll
    for (int tt=0; tt<4; ++tt){
      const float gsc = (tt == 2) ? C2L : LOG2E;
      float bias = 0.f;
      if (l15 < 2){
        const int grow = tt*H2 + 48 + l15;
#pragma unroll
        for (int kt=0; kt<2; ++kt){
#pragma unroll
          for (int j=0;j<8;j++){
            const int kk = kt*32 + quad*8 + j;
            float w = 0.f;
            if (kk < H2)         w = w_hh2[grow*H2 + kk];
            else if (kk < H2+H1) w = w_ih2[grow*H1 + (kk-H2)];
            w *= gsc;
            short hi, lo; wsplit(w, hi, lo);
            Bh[tt][kt][j] = hi; Bl[tt][kt][j] = lo;
          }
        }
        bias = gsc * (b_ih2[grow] + b_hh2[grow]);
      } else if (l15 < 7){
        const int e = l15 - 2;
        const int grow = tt*H1 + e;
#pragma unroll
        for (int j=0;j<8;j++){
          const int kk = 32 + quad*8 + j;   // chunk1 global k (h1 at 50..54)
          float w1 = (kk >= H2 && kk < H2+H1) ? gsc * w_hh1[grow*H1 + (kk-H2)] : 0.f;
          short hi, lo; wsplit(w1, hi, lo);
          Bh[tt][1][j] = hi; Bl[tt][1][j] = lo;
          const int k2 = quad*8 + j;        // chunk2 k (x dims)
          float w2 = (k2 < IN_DIM) ? gsc * w_ih1[grow*IN_DIM + k2] : 0.f;
          wsplit(w2, hi, lo);
          Bh[tt][2][j] = hi; Bl[tt][2][j] = lo;
        }
        bias = gsc * (b_ih1[grow] + b_hh1[grow]);
      }
      biasv[tt][0]=bias; biasv[tt][1]=bias; biasv[tt][2]=bias; biasv[tt][3]=bias;
    }
  }

  // ---- zero LDS state ----
  { unsigned short* p = &a2h[0][0]; for (int i=tid;i<2*16*72;i+=256) p[i]=0; }
  { unsigned short* p = &a2l[0][0]; for (int i=tid;i<2*16*72;i+=256) p[i]=0; }

  // ---- x fragments (wave 3 only): lane(l15=batch, quad<2 -> dims quad*8+j) ----
  bf16x8 XAh = zero8, XAl = zero8, XBh = zero8, XBl = zero8;
  float4 pa, pb;
  const bool xact = (wave == 3) && (quad < 2);
  const float* xbase = &x[(size_t)(b0+l15)*T_STEPS*IN_DIM + quad*8];
  if (xact){
    float4 a0 = *(const float4*)(xbase + 0);
    float4 a1 = *(const float4*)(xbase + 4);
    xsplit(a0, a1, XAh, XAl);                 // XA = x(0)
    pa = *(const float4*)(xbase + 1*IN_DIM);  // pf = x(1)
    pb = *(const float4*)(xbase + 1*IN_DIM + 4);
  }
  __syncthreads();   // zeros + nothing else pending

#define ROTATE(XH_, XL_, SN_) do { \
    if (xact){ \
      xsplit(pa, pb, XH_, XL_); \
      const int sn_ = (SN_) < T_STEPS ? (SN_) : T_STEPS-1; \
      const float* xp_ = xbase + (size_t)sn_*IN_DIM; \
      pa = *(const float4*)xp_; \
      pb = *(const float4*)(xp_ + 4); \
    } } while(0)

#define ACT_BLOCK(ACC_, HV_) \
    _Pragma("unroll") \
    for (int r=0;r<4;r++){ \
      float gi = rcp1pexp2(-ACC_[0][r]); \
      float gf = rcp1pexp2(-ACC_[1][r]); \
      float gg = fmaf(-C2L2, rcp1pexp2(ACC_[2][r]), C2L); /* = C2L*tanh */ \
      float go = rcp1pexp2(-ACC_[3][r]); \
      cst[r] = fmaf(gf, cst[r], gi * gg); \
      HV_[r] = go * fmaf(-2.0f, rcp1pexp2(cst[r]), 1.0f); \
    }

#define MAIN_BODY(T_, RD_, WR_, XCH_, XCL_, XNH_, XNL_) do { \
    const int rb_ = l15*72; \
    bf16x8 ah0 = *(const bf16x8*)&a2h[RD_][rb_ +      quad*8]; \
    bf16x8 al0 = *(const bf16x8*)&a2l[RD_][rb_ +      quad*8]; \
    bf16x8 ah1 = *(const bf16x8*)&a2h[RD_][rb_ + 32 + quad*8]; \
    bf16x8 al1 = *(const bf16x8*)&a2l[RD_][rb_ + 32 + quad*8]; \
    if (wave == 3) ROTATE(XNH_, XNL_, (T_)+3);  /* fills LDS-read latency */ \
    f32x4 acc[4]; \
    if (wave < 3){ \
      _Pragma("unroll") \
      for (int tt=0; tt<4; ++tt){ \
        f32x4 c0 = __builtin_amdgcn_mfma_f32_16x16x32_bf16(ah0, Bh[tt][0], biasv[tt], 0,0,0); \
        c0 = __builtin_amdgcn_mfma_f32_16x16x32_bf16(al0, Bh[tt][0], c0, 0,0,0); \
        c0 = __builtin_amdgcn_mfma_f32_16x16x32_bf16(ah0, Bl[tt][0], c0, 0,0,0); \
        f32x4 c1 = __builtin_amdgcn_mfma_f32_16x16x32_bf16(ah1, Bh[tt][1], zero4, 0,0,0); \
        c1 = __builtin_amdgcn_mfma_f32_16x16x32_bf16(al1, Bh[tt][1], c1, 0,0,0); \
        c1 = __builtin_amdgcn_mfma_f32_16x16x32_bf16(ah1, Bl[tt][1], c1, 0,0,0); \
        acc[tt] = c0 + c1; \
      } \
    } else { \
      _Pragma("unroll") \
      for (int tt=0; tt<4; ++tt){ \
        f32x4 c0 = __builtin_amdgcn_mfma_f32_16x16x32_bf16(ah0, Bh[tt][0], biasv[tt], 0,0,0); \
        c0 = __builtin_amdgcn_mfma_f32_16x16x32_bf16(al0, Bh[tt][0], c0, 0,0,0); \
        c0 = __builtin_amdgcn_mfma_f32_16x16x32_bf16(ah0, Bl[tt][0], c0, 0,0,0); \
        f32x4 c1 = __builtin_amdgcn_mfma_f32_16x16x32_bf16(ah1, Bh[tt][1], zero4, 0,0,0); \
        c1 = __builtin_amdgcn_mfma_f32_16x16x32_bf16(al1, Bh[tt][1], c1, 0,0,0); \
        c1 = __builtin_amdgcn_mfma_f32_16x16x32_bf16(ah1, Bl[tt][1], c1, 0,0,0); \
        f32x4 c2 = __builtin_amdgcn_mfma_f32_16x16x32_bf16(XCH_, Bh[tt][2], zero4, 0,0,0); \
        c2 = __builtin_amdgcn_mfma_f32_16x16x32_bf16(XCL_, Bh[tt][2], c2, 0,0,0); \
        c2 = __builtin_amdgcn_mfma_f32_16x16x32_bf16(XCH_, Bl[tt][2], c2, 0,0,0); \
        acc[tt] = (c0 + c1) + c2; \
      } \
    } \
    float hv[4]; \
    ACT_BLOCK(acc, hv) \
    if (wave < 3){ \
      const int wrb = quad*4*72 + wave*16 + l15; \
      _Pragma("unroll") \
      for (int r=0;r<4;r++){ \
        unsigned short hh, hl; split1(hv[r], hh, hl); \
        a2h[WR_][wrb + r*72] = hh; \
        a2l[WR_][wrb + r*72] = hl; \
      } \
      if ((T_) == T_STEPS-1){ \
        _Pragma("unroll") \
        for (int r=0;r<4;r++){ \
          out[(size_t)B_TOTAL*NCLS + (size_t)(b0+quad*4+r)*H2 + wave*16+l15] = hv[r]; \
          h2f[(quad*4+r)*52 + wave*16+l15] = hv[r]; \
        } \
      } \
    } else if (l15 < 7){ \
      const int wrb = quad*4*72 + 48 + l15;  /* 48,49=h2 | 50..54=h1 */ \
      _Pragma("unroll") \
      for (int r=0;r<4;r++){ \
        unsigned short hh, hl; split1(hv[r], hh, hl); \
        a2h[WR_][wrb + r*72] = hh; \
        a2l[WR_][wrb + r*72] = hl; \
      } \
      if ((T_) == T_STEPS-1 && l15 < 2){ \
        _Pragma("unroll") \
        for (int r=0;r<4;r++){ \
          out[(size_t)B_TOTAL*NCLS + (size_t)(b0+quad*4+r)*H2 + 48+l15] = hv[r]; \
          h2f[(quad*4+r)*52 + 48+l15] = hv[r]; \
        } \
      } \
    } \
  } while(0)

  // ---- peel t=-1: wave 3 computes h1(0) = f(0, x(0)) into a2[0] ----
  if (wave == 3){
    f32x4 acc[4];
#pragma unroll
    for (int tt=0; tt<4; ++tt){
      f32x4 c2 = __builtin_amdgcn_mfma_f32_16x16x32_bf16(XAh, Bh[tt][2], biasv[tt], 0,0,0);
      c2 = __builtin_amdgcn_mfma_f32_16x16x32_bf16(XAl, Bh[tt][2], c2, 0,0,0);
      c2 = __builtin_amdgcn_mfma_f32_16x16x32_bf16(XAh, Bl[tt][2], c2, 0,0,0);
      acc[tt] = c2;
    }
    ROTATE(XBh, XBl, 2);          // XB = x(1); prefetch x(2)
    const bool isl1 = (l15 >= 2) && (l15 < 7);
#pragma unroll
    for (int r=0;r<4;r++){
      float gi = rcp1pexp2(-acc[0][r]);
      float gf = rcp1pexp2(-acc[1][r]);
      float gg = fmaf(-C2L2, rcp1pexp2(acc[2][r]), C2L);
      float go = rcp1pexp2(-acc[3][r]);
      float cn = fmaf(gf, cst[r], gi * gg);
      if (isl1){
        cst[r] = cn;
        float h = go * fmaf(-2.0f, rcp1pexp2(cn), 1.0f);
        unsigned short hh, hl; split1(h, hh, hl);
        const int row = quad*4 + r;
        a2h[0][row*72 + 48 + l15] = hh;
        a2l[0][row*72 + 48 + l15] = hl;
      }
    }
  }
  LDS_FENCE(); BARRIER();

  // main loop, unrolled x2: compile-time buffer parity and X ping-pong
  for (int t2 = 0; t2 < T_STEPS; t2 += 2){
    MAIN_BODY(t2,   0, 1, XBh, XBl, XAh, XAl);  // uses x(t2+1)=XB, fills XA
    LDS_FENCE(); BARRIER();
    MAIN_BODY(t2+1, 1, 0, XAh, XAl, XBh, XBl);  // uses x(t2+2)=XA, fills XB
    LDS_FENCE(); BARRIER();
  }

#undef MAIN_BODY
#undef ACT_BLOCK
#undef ROTATE

  __syncthreads();
  // fused FC: 16 batches x 20 outputs = 320 results on 256 threads
  for (int i = tid; i < 16*NCLS; i += 256){
    const int b = i / NCLS, o = i % NCLS;
    float s = fc_b[o];
#pragma unroll 10
    for (int k=0;k<H2;k++) s += fc_w[o*H2+k] * h2f[b*52+k];
    out[(size_t)(b0+b)*NCLS + o] = s;
  }
}

extern "C" void kernel_launch(void* const* d_in, const int* in_sizes, int n_in,
                              void* d_out, int out_size, void* d_ws, size_t ws_size,
                              hipStream_t stream) {
  const float* x     = (const float*)d_in[0];
  const float* w_ih1 = (const float*)d_in[1];
  const float* w_hh1 = (const float*)d_in[2];
  const float* b_ih1 = (const float*)d_in[3];
  const float* b_hh1 = (const float*)d_in[4];
  const float* w_ih2 = (const float*)d_in[5];
  const float* w_hh2 = (const float*)d_in[6];
  const float* b_ih2 = (const float*)d_in[7];
  const float* b_hh2 = (const float*)d_in[8];
  const float* fc_w  = (const float*)d_in[9];
  const float* fc_b  = (const float*)d_in[10];
  float* out = (float*)d_out;

  lstm_fused_kernel<<<dim3(B_TOTAL/16), dim3(256), 0, stream>>>(
      x, w_ih1, w_hh1, b_ih1, b_hh1, w_ih2, w_hh2, b_ih2, b_hh2, fc_w, fc_b, out);
}